// Round 1
// baseline (425.827 us; speedup 1.0000x reference)
//
#include <hip/hip_runtime.h>

typedef unsigned short u16;
typedef __bf16 bf16x8 __attribute__((ext_vector_type(8)));
typedef float f32x4 __attribute__((ext_vector_type(4)));
typedef u16 u16x8 __attribute__((ext_vector_type(8), may_alias));
typedef u16 u16x4 __attribute__((ext_vector_type(4), may_alias));

#define D_MODEL 1024
#define D_MLP   4096
#define D_HEAD  64
#define N_HEADS 16
#define SEQ     2048
#define BATCH   2
#define BS      (BATCH * SEQ)   // 4096 rows
#define QKV_LD  3072
#define OFF_Q   0
#define OFF_K   1024
#define OFF_V   2048

__device__ __forceinline__ u16 f2b(float f) {
  unsigned u = __builtin_bit_cast(unsigned, f);
  u += 0x7fffu + ((u >> 16) & 1u);           // round-to-nearest-even
  return (u16)(u >> 16);
}

__device__ __forceinline__ void gload_lds16(const u16* g, u16* l) {
  __builtin_amdgcn_global_load_lds(
      (const __attribute__((address_space(1))) unsigned int*)g,
      (__attribute__((address_space(3))) unsigned int*)l, 16, 0, 0);
}

// ---------------- fp32 -> bf16 convert (4 elems/thread) ----------------
__global__ __launch_bounds__(256) void cvt_kernel(const float* __restrict__ in,
                                                  u16* __restrict__ out, int n4) {
  int i = blockIdx.x * 256 + threadIdx.x;
  if (i >= n4) return;
  float4 v = ((const float4*)in)[i];
  u16x4 o;
  o[0] = f2b(v.x); o[1] = f2b(v.y); o[2] = f2b(v.z); o[3] = f2b(v.w);
  ((u16x4*)out)[i] = o;
}

// ---------------- generic bf16 GEMM: C[M,N] = A[M,K] @ B[N,K]^T ----------------
// 128x128 tile, BK=64, 4 waves, 16x16x32 MFMA, global_load_lds(16B),
// XOR slot-swizzle applied to the GLOBAL source (LDS stays linear) + same XOR on reads.
// MODE 0: outb = bf16(acc)                                   (qkv)
// MODE 1: o = acc + resid[idx]; outf = o; outb = bf16(o)     (attn out + residual)
// MODE 2: o = relu(acc + bias[col]); outb = bf16(o)          (mlp in)
// MODE 3: outf = acc + resid[idx] + bias[col]                (mlp out -> d_out)
template<int MODE>
__global__ __launch_bounds__(256) void gemm_bt(
    const u16* __restrict__ A, const u16* __restrict__ Bw,
    int M, int N, int K,
    u16* __restrict__ outb, float* __restrict__ outf,
    const float* __restrict__ resid, const float* __restrict__ bias)
{
  __shared__ u16 Asm_[128 * 64];
  __shared__ u16 Bsm_[128 * 64];
  const int t = threadIdx.x;
  const int lane = t & 63;
  const int l15 = lane & 15, l4 = lane >> 4;
  const int w = t >> 6;
  const int wr = w >> 1, wc = w & 1;
  const int m0 = blockIdx.y * 128;
  const int n0 = blockIdx.x * 128;

  f32x4 acc[4][4] = {};

  for (int k0 = 0; k0 < K; k0 += 64) {
    __syncthreads();
#pragma unroll
    for (int i = 0; i < 4; ++i) {
      int s = i * 256 + t;                 // 16B slot index 0..1023
      int row = s >> 3;
      int sl = s & 7;
      int gc = ((sl ^ (row & 7)) << 3);    // pre-swizzled global k-chunk
      const u16* ga = A + (size_t)(m0 + row) * K + (k0 + gc);
      const u16* gb = Bw + (size_t)(n0 + row) * K + (k0 + gc);
      u16* la = Asm_ + (i * 256 + (t & ~63)) * 8;   // wave-uniform base
      u16* lb = Bsm_ + (i * 256 + (t & ~63)) * 8;
      gload_lds16(ga, la);
      gload_lds16(gb, lb);
    }
    asm volatile("s_waitcnt vmcnt(0)" ::: "memory");
    __syncthreads();
#pragma unroll
    for (int kk = 0; kk < 2; ++kk) {
      bf16x8 af[4], bfr[4];
#pragma unroll
      for (int mi = 0; mi < 4; ++mi) {
        int row = wr * 64 + mi * 16 + l15;
        int sl2 = (kk * 4 + l4) ^ (row & 7);
        u16x8 ua = *(const u16x8*)(Asm_ + row * 64 + sl2 * 8);
        af[mi] = __builtin_bit_cast(bf16x8, ua);
      }
#pragma unroll
      for (int ni = 0; ni < 4; ++ni) {
        int row = wc * 64 + ni * 16 + l15;
        int sl2 = (kk * 4 + l4) ^ (row & 7);
        u16x8 ub = *(const u16x8*)(Bsm_ + row * 64 + sl2 * 8);
        bfr[ni] = __builtin_bit_cast(bf16x8, ub);
      }
#pragma unroll
      for (int mi = 0; mi < 4; ++mi)
#pragma unroll
        for (int ni = 0; ni < 4; ++ni)
          acc[mi][ni] = __builtin_amdgcn_mfma_f32_16x16x32_bf16(af[mi], bfr[ni], acc[mi][ni], 0, 0, 0);
    }
  }

#pragma unroll
  for (int mi = 0; mi < 4; ++mi) {
    int rowb = m0 + wr * 64 + mi * 16 + l4 * 4;
#pragma unroll
    for (int ni = 0; ni < 4; ++ni) {
      int col = n0 + wc * 64 + ni * 16 + l15;
#pragma unroll
      for (int r = 0; r < 4; ++r) {
        float v = acc[mi][ni][r];
        size_t idx = (size_t)(rowb + r) * N + col;
        if (MODE == 0) {
          outb[idx] = f2b(v);
        } else if (MODE == 1) {
          float o = v + resid[idx];
          outf[idx] = o;
          outb[idx] = f2b(o);
        } else if (MODE == 2) {
          float o = v + bias[col];
          o = o > 0.f ? o : 0.f;
          outb[idx] = f2b(o);
        } else {
          outf[idx] = v + resid[idx] + bias[col];
        }
      }
    }
  }
}

// ---------------- causal flash attention ----------------
// One wave per (b, h, 16 query rows). Key tiles of 32. qkv layout [BS][3072]: Q|K|V.
__global__ __launch_bounds__(256) void attn_kernel(const u16* __restrict__ qkv,
                                                   u16* __restrict__ zb)
{
  __shared__ u16 Vt[4][64][40];   // per-wave, V transposed [d][p], padded rows (80B, 16B-aligned)
  __shared__ u16 Pl[4][16][40];   // per-wave, P [q][p]
  const int t = threadIdx.x;
  const int w = t >> 6, lane = t & 63;
  const int l15 = lane & 15, l4 = lane >> 4;
  const int u = blockIdx.x * 4 + w;
  const int qt = u >> 5;                 // 128 q-tiles per (b,h); B*H = 32
  const int bh = u & 31;
  const int b = bh >> 4, h = bh & 15;
  const int q0 = qt * 16;
  const u16* base = qkv + (size_t)b * SEQ * QKV_LD;

  bf16x8 qf[2];
#pragma unroll
  for (int kc = 0; kc < 2; ++kc) {
    u16x8 uq = *(const u16x8*)(base + (size_t)(q0 + l15) * QKV_LD + OFF_Q + h * 64 + kc * 32 + l4 * 8);
    qf[kc] = __builtin_bit_cast(bf16x8, uq);
  }

  f32x4 zacc[4] = {};
  float m_run[4], l_run[4];
#pragma unroll
  for (int r = 0; r < 4; ++r) { m_run[r] = -1e30f; l_run[r] = 0.f; }

  const int ntiles = ((q0 + 15) >> 5) + 1;
  for (int pt = 0; pt < ntiles; ++pt) {
    const int p0 = pt * 32;
    // stage V tile transposed: Vt[d][p]
#pragma unroll
    for (int i = 0; i < 4; ++i) {
      int pl = i * 8 + (lane >> 3);
      int d0 = (lane & 7) * 8;
      u16x8 vv = *(const u16x8*)(base + (size_t)(p0 + pl) * QKV_LD + OFF_V + h * 64 + d0);
#pragma unroll
      for (int j = 0; j < 8; ++j) Vt[w][d0 + j][pl] = vv[j];
    }
    // scores: D[q,key] = sum_d Q[q,d] K[key,d]
    f32x4 sf[2] = {};
#pragma unroll
    for (int sub = 0; sub < 2; ++sub) {
#pragma unroll
      for (int kc = 0; kc < 2; ++kc) {
        u16x8 uk = *(const u16x8*)(base + (size_t)(p0 + sub * 16 + l15) * QKV_LD + OFF_K + h * 64 + kc * 32 + l4 * 8);
        bf16x8 kf = __builtin_bit_cast(bf16x8, uk);
        sf[sub] = __builtin_amdgcn_mfma_f32_16x16x32_bf16(qf[kc], kf, sf[sub], 0, 0, 0);
      }
    }
    // scale + causal mask
    const int qrow = q0 + l4 * 4;
#pragma unroll
    for (int sub = 0; sub < 2; ++sub) {
      int pcol = p0 + sub * 16 + l15;
#pragma unroll
      for (int r = 0; r < 4; ++r) {
        float s = sf[sub][r] * 0.125f;
        sf[sub][r] = (pcol > qrow + r) ? -1e30f : s;
      }
    }
    // online softmax (reduce across the 16 lanes of each row group)
    float mt[4], rs[4], pvv[2][4];
#pragma unroll
    for (int r = 0; r < 4; ++r) mt[r] = fmaxf(sf[0][r], sf[1][r]);
#pragma unroll
    for (int off = 1; off < 16; off <<= 1)
#pragma unroll
      for (int r = 0; r < 4; ++r) mt[r] = fmaxf(mt[r], __shfl_xor(mt[r], off));
#pragma unroll
    for (int r = 0; r < 4; ++r) {
      float mn = fmaxf(m_run[r], mt[r]);
      float sc = __expf(m_run[r] - mn);
      m_run[r] = mn;
      l_run[r] *= sc;
#pragma unroll
      for (int dn = 0; dn < 4; ++dn) zacc[dn][r] *= sc;
      pvv[0][r] = __expf(sf[0][r] - mn);
      pvv[1][r] = __expf(sf[1][r] - mn);
      rs[r] = pvv[0][r] + pvv[1][r];
    }
#pragma unroll
    for (int off = 1; off < 16; off <<= 1)
#pragma unroll
      for (int r = 0; r < 4; ++r) rs[r] += __shfl_xor(rs[r], off);
#pragma unroll
    for (int r = 0; r < 4; ++r) l_run[r] += rs[r];
    // P -> LDS (re-layout C-frag -> A-frag)
#pragma unroll
    for (int sub = 0; sub < 2; ++sub)
#pragma unroll
      for (int r = 0; r < 4; ++r)
        Pl[w][l4 * 4 + r][sub * 16 + l15] = f2b(pvv[sub][r]);
    // PV: z[q,d] += sum_p P[q,p] V[p,d]
    u16x8 up = *(const u16x8*)&Pl[w][l15][l4 * 8];
    bf16x8 pa = __builtin_bit_cast(bf16x8, up);
#pragma unroll
    for (int dn = 0; dn < 4; ++dn) {
      u16x8 uv = *(const u16x8*)&Vt[w][dn * 16 + l15][l4 * 8];
      bf16x8 vb = __builtin_bit_cast(bf16x8, uv);
      zacc[dn] = __builtin_amdgcn_mfma_f32_16x16x32_bf16(pa, vb, zacc[dn], 0, 0, 0);
    }
  }
  // write z in [B,S,H*Dh] bf16
#pragma unroll
  for (int r = 0; r < 4; ++r) {
    float inv = 1.f / l_run[r];
    int q = q0 + l4 * 4 + r;
#pragma unroll
    for (int dn = 0; dn < 4; ++dn) {
      int d = dn * 16 + l15;
      zb[((size_t)b * SEQ + q) * D_MODEL + h * 64 + d] = f2b(zacc[dn][r] * inv);
    }
  }
}

// ---------------- launch ----------------
extern "C" void kernel_launch(void* const* d_in, const int* in_sizes, int n_in,
                              void* d_out, int out_size, void* d_ws, size_t ws_size,
                              hipStream_t stream) {
  const float* x     = (const float*)d_in[0];
  const float* W_K   = (const float*)d_in[1];
  const float* W_Q   = (const float*)d_in[2];
  const float* W_V   = (const float*)d_in[3];
  const float* W_O   = (const float*)d_in[4];
  const float* W_in  = (const float*)d_in[5];
  const float* b_in  = (const float*)d_in[6];
  const float* W_out = (const float*)d_in[7];
  const float* b_out = (const float*)d_in[8];
  float* out = (float*)d_out;

  char* p = (char*)d_ws;
  u16* xb    = (u16*)p;            p += (size_t)BS * D_MODEL * 2;
  u16* wqkv  = (u16*)p;            p += (size_t)QKV_LD * D_MODEL * 2;
  u16* wo_b  = (u16*)p;            p += (size_t)D_MODEL * D_MODEL * 2;
  u16* win_b = (u16*)p;            p += (size_t)D_MLP * D_MODEL * 2;
  u16* wout_b= (u16*)p;            p += (size_t)D_MODEL * D_MLP * 2;
  u16* qkv   = (u16*)p;            p += (size_t)BS * QKV_LD * 2;
  u16* zb    = (u16*)p;            p += (size_t)BS * D_MODEL * 2;
  float* x1f = (float*)p;          p += (size_t)BS * D_MODEL * 4;
  u16* x1b   = (u16*)p;            p += (size_t)BS * D_MODEL * 2;
  u16* hb    = (u16*)p;            p += (size_t)BS * D_MLP * 2;

  auto cvt = [&](const float* src, u16* dst, int n) {
    int n4 = n / 4;
    cvt_kernel<<<(n4 + 255) / 256, 256, 0, stream>>>(src, dst, n4);
  };
  cvt(x, xb, BS * D_MODEL);
  cvt(W_Q, wqkv + 0,                  N_HEADS * D_HEAD * D_MODEL);
  cvt(W_K, wqkv + 1024 * 1024,        N_HEADS * D_HEAD * D_MODEL);
  cvt(W_V, wqkv + 2 * 1024 * 1024,    N_HEADS * D_HEAD * D_MODEL);
  cvt(W_O, wo_b,  D_MODEL * D_MODEL);
  cvt(W_in, win_b, D_MLP * D_MODEL);
  cvt(W_out, wout_b, D_MODEL * D_MLP);

  // QKV projection: [4096,1024] @ [3072,1024]^T -> qkv [4096,3072]
  gemm_bt<0><<<dim3(QKV_LD / 128, BS / 128), 256, 0, stream>>>(
      xb, wqkv, BS, QKV_LD, D_MODEL, qkv, nullptr, nullptr, nullptr);

  // attention: 4096 wave-units / 4 per block
  attn_kernel<<<dim3(BS * N_HEADS / 16 / 4), 256, 0, stream>>>(qkv, zb);

  // attn out + residual: z @ W_O^T + x -> x1 (f32 + bf16)
  gemm_bt<1><<<dim3(D_MODEL / 128, BS / 128), 256, 0, stream>>>(
      zb, wo_b, BS, D_MODEL, D_MODEL, x1b, x1f, x, nullptr);

  // MLP in: relu(x1 @ W_in^T + b_in) -> h
  gemm_bt<2><<<dim3(D_MLP / 128, BS / 128), 256, 0, stream>>>(
      x1b, win_b, BS, D_MLP, D_MODEL, hb, nullptr, nullptr, b_in);

  // MLP out: x1 + h @ W_out^T + b_out -> out (f32)
  gemm_bt<3><<<dim3(D_MODEL / 128, BS / 128), 256, 0, stream>>>(
      hb, wout_b, BS, D_MODEL, D_MLP, nullptr, out, x1f, b_out);
}